// Round 1
// baseline (215.105 us; speedup 1.0000x reference)
//
#include <hip/hip_runtime.h>

typedef unsigned short u16;
typedef __attribute__((ext_vector_type(8))) short bf16x8;
typedef __attribute__((ext_vector_type(4))) float f32x4;

#define NB 4
#define NT 1024
#define NC 768
#define NH 12
#define HD 64

__device__ __forceinline__ u16 f2bf(float f) {
  union { float f; unsigned u; } v; v.f = f;
  unsigned r = v.u + 0x7FFFu + ((v.u >> 16) & 1u);
  return (u16)(r >> 16);
}
__device__ __forceinline__ float bf2f(u16 h) {
  union { unsigned u; float f; } v; v.u = ((unsigned)h) << 16;
  return v.f;
}

// ---------------- conversion kernels ----------------
__global__ __launch_bounds__(256) void conv_x_k(const float* __restrict__ x,
                                                u16* __restrict__ xb, int n) {
  int i = blockIdx.x * 256 + threadIdx.x;
  if (i < n) xb[i] = f2bf(x[i]);
}

// Wq/Wk/Wv/Wproj are [k][n] row-major fp32; produce Wt[n][k] bf16 (QKV concat) and Wtp[n][k]
__global__ __launch_bounds__(256) void conv_w_k(const float* __restrict__ Wq,
                                                const float* __restrict__ Wk,
                                                const float* __restrict__ Wv,
                                                const float* __restrict__ Wp,
                                                u16* __restrict__ Wt,
                                                u16* __restrict__ Wtp) {
  int idx = blockIdx.x * 256 + threadIdx.x;  // 768*768
  int k = idx / NC, n = idx - k * NC;
  Wt[(size_t)(0    + n) * NC + k] = f2bf(Wq[idx]);
  Wt[(size_t)(768  + n) * NC + k] = f2bf(Wk[idx]);
  Wt[(size_t)(1536 + n) * NC + k] = f2bf(Wv[idx]);
  Wtp[(size_t)n * NC + k]         = f2bf(Wp[idx]);
}

// ---------------- FIRE bias table: bias[h][q][rel], rel in [0,256] ----------------
__global__ __launch_bounds__(256) void fire_bias_k(const float* __restrict__ w1,
                                                   const float* __restrict__ b1,
                                                   const float* __restrict__ w2,
                                                   const float* __restrict__ b2,
                                                   const float* __restrict__ cP,
                                                   const float* __restrict__ LmP,
                                                   float* __restrict__ bias) {
  int q = blockIdx.x;
  float c = cP[0], Lm = LmP[0];
  float thresh = fabsf(Lm * 512.0f);
  float pn = fmaxf((float)q, thresh);
  float inv_nl = 1.0f / (logf(fabsf(c * pn) + 1.0f) + 1e-6f);
  for (int rel = threadIdx.x; rel < 257; rel += 256) {
    float z = logf(fabsf(c * (float)rel) + 1.0f) * inv_nl;
    float acc[NH];
#pragma unroll
    for (int hh = 0; hh < NH; ++hh) acc[hh] = b2[hh];
#pragma unroll
    for (int j = 0; j < 32; ++j) {
      float hj = fmaxf(z * w1[j] + b1[j], 0.0f);
#pragma unroll
      for (int hh = 0; hh < NH; ++hh) acc[hh] += hj * w2[j * NH + hh];
    }
#pragma unroll
    for (int hh = 0; hh < NH; ++hh)
      bias[((size_t)hh * NT + q) * 257 + rel] = acc[hh];
  }
}

// ---------------- GEMM: A[M][K] bf16 row-major, Bt[N][K] bf16 (B transposed) ----------------
// block = 256 thr = 4 waves; block tile 128x128, wave tile 64x64 (4x4 of 16x16 MFMA)
template <bool F32OUT>
__global__ __launch_bounds__(256) void gemm_bt(const u16* __restrict__ A,
                                               const u16* __restrict__ Bt,
                                               void* __restrict__ Cv,
                                               int M, int N, int K) {
  const int wid = threadIdx.x >> 6, lane = threadIdx.x & 63;
  const int wr = wid >> 1, wc = wid & 1;
  const int m0 = blockIdx.x * 128 + wr * 64;
  const int n0 = blockIdx.y * 128 + wc * 64;
  const int lr = lane & 15, lk = (lane >> 4) << 3;
  f32x4 acc[4][4] = {};
  const u16* Ap = A + (size_t)(m0 + lr) * K + lk;
  const u16* Bp = Bt + (size_t)(n0 + lr) * K + lk;
  for (int k0 = 0; k0 < K; k0 += 32) {
    bf16x8 af[4], bfr[4];
#pragma unroll
    for (int i = 0; i < 4; ++i)
      af[i] = *(const bf16x8*)(Ap + (size_t)i * 16 * K + k0);
#pragma unroll
    for (int j = 0; j < 4; ++j)
      bfr[j] = *(const bf16x8*)(Bp + (size_t)j * 16 * K + k0);
#pragma unroll
    for (int i = 0; i < 4; ++i)
#pragma unroll
      for (int j = 0; j < 4; ++j)
        acc[i][j] = __builtin_amdgcn_mfma_f32_16x16x32_bf16(af[i], bfr[j], acc[i][j], 0, 0, 0);
  }
  const int rbase = (lane >> 4) * 4;
#pragma unroll
  for (int i = 0; i < 4; ++i)
#pragma unroll
    for (int j = 0; j < 4; ++j)
#pragma unroll
      for (int r = 0; r < 4; ++r) {
        size_t row = m0 + i * 16 + rbase + r;
        size_t col = n0 + j * 16 + lr;
        if (F32OUT)
          ((float*)Cv)[row * N + col] = acc[i][j][r];
        else
          ((u16*)Cv)[row * N + col] = f2bf(acc[i][j][r]);
      }
}

// ---------------- RoPE + head split: qkv[4096][2304] -> Q,K (bh,t,d), Vt (bh,d,t) ----------------
__global__ __launch_bounds__(256) void rope_split_k(const u16* __restrict__ qkv,
                                                    u16* __restrict__ Q,
                                                    u16* __restrict__ K,
                                                    u16* __restrict__ Vt) {
  int idx = blockIdx.x * 256 + threadIdx.x;  // 48*1024*64
  int d = idx & 63;
  int t = (idx >> 6) & 1023;
  int bh = idx >> 16;
  int b = bh / NH, h = bh - b * NH;
  size_t row = (size_t)(b * NT + t) * 2304 + h * HD;
  int i = d & 31;
  float inv = __expf(-(float)i * (0.03125f * 9.2103403719761836f));  // 10000^(-i/32)
  float ang = (float)t * inv;
  float s, c;
  sincosf(ang, &s, &c);
  float qa = bf2f(qkv[row + i]);
  float qb = bf2f(qkv[row + i + 32]);
  float ka = bf2f(qkv[row + 768 + i]);
  float kb = bf2f(qkv[row + 768 + i + 32]);
  float qv = (d < 32) ? (qa * c - qb * s) : (qa * s + qb * c);
  float kv = (d < 32) ? (ka * c - kb * s) : (ka * s + kb * c);
  size_t base = (size_t)bh << 16;  // 1024*64
  Q[base + t * HD + d] = f2bf(qv);
  K[base + t * HD + d] = f2bf(kv);
  Vt[base + (size_t)d * NT + t] = qkv[row + 1536 + d];
}

// ---------------- windowed flash attention ----------------
// grid (48, 16); 4 waves/block; wave handles 16 queries of one (b,h)
__global__ __launch_bounds__(256) void attn_k(const u16* __restrict__ Q,
                                              const u16* __restrict__ K,
                                              const u16* __restrict__ Vt,
                                              const float* __restrict__ bias,
                                              u16* __restrict__ Y) {
  __shared__ __align__(16) u16 plds[4][16][32];
  const int bh = blockIdx.x;
  const int b = bh / NH, h = bh - b * NH;
  const int wid = threadIdx.x >> 6, lane = threadIdx.x & 63;
  const int qt = blockIdx.y * 4 + wid;
  const int q0 = qt << 4;
  const int lr = lane & 15, lg = lane >> 4, lk = (lane >> 4) << 3;
  const u16* Qb = Q + ((size_t)bh << 16);
  const u16* Kb = K + ((size_t)bh << 16);
  const u16* Vb = Vt + ((size_t)bh << 16);
  const float* biash = bias + (size_t)h * NT * 257;

  bf16x8 aq0 = *(const bf16x8*)(Qb + (q0 + lr) * HD + lk);
  bf16x8 aq1 = *(const bf16x8*)(Qb + (q0 + lr) * HD + 32 + lk);
  f32x4 yacc[4] = {};
  float mrun[4] = {-1e30f, -1e30f, -1e30f, -1e30f};
  float lrun[4] = {0.f, 0.f, 0.f, 0.f};
  u16(*pl)[32] = plds[wid];

  int kt0 = q0 - 256;
  kt0 = (kt0 > 0 ? kt0 : 0) >> 4;
  for (int kt = kt0; kt <= qt; ++kt) {
    const int kb = kt << 4;
    bf16x8 bk0 = *(const bf16x8*)(Kb + (kb + lr) * HD + lk);
    bf16x8 bk1 = *(const bf16x8*)(Kb + (kb + lr) * HD + 32 + lk);
    f32x4 s = {};
    s = __builtin_amdgcn_mfma_f32_16x16x32_bf16(aq0, bk0, s, 0, 0, 0);
    s = __builtin_amdgcn_mfma_f32_16x16x32_bf16(aq1, bk1, s, 0, 0, 0);
    const int kcol = kb + lr;
    float sv[4];
#pragma unroll
    for (int r = 0; r < 4; ++r) {
      int qrow = q0 + lg * 4 + r;
      int rel = qrow - kcol;
      if (rel >= 0 && rel <= 256)
        sv[r] = s[r] * 0.125f + biash[(size_t)qrow * 257 + rel];
      else
        sv[r] = -1e30f;
    }
    float scale[4], pexp[4];
#pragma unroll
    for (int r = 0; r < 4; ++r) {
      float m = sv[r];
#pragma unroll
      for (int off = 1; off < 16; off <<= 1)
        m = fmaxf(m, __shfl_xor(m, off, 64));
      float mn = fmaxf(mrun[r], m);
      scale[r] = __expf(mrun[r] - mn);
      mrun[r] = mn;
      pexp[r] = __expf(sv[r] - mn);
      float ss = pexp[r];
#pragma unroll
      for (int off = 1; off < 16; off <<= 1)
        ss += __shfl_xor(ss, off, 64);
      lrun[r] = lrun[r] * scale[r] + ss;
    }
#pragma unroll
    for (int dt = 0; dt < 4; ++dt)
#pragma unroll
      for (int r = 0; r < 4; ++r) yacc[dt][r] *= scale[r];
    // stage P (16 queries x 32 keys, upper 16 keys zero)
#pragma unroll
    for (int r = 0; r < 4; ++r) {
      pl[lg * 4 + r][lr] = f2bf(pexp[r]);
      pl[lg * 4 + r][16 + lr] = 0;
    }
    asm volatile("s_waitcnt lgkmcnt(0)" ::: "memory");
    bf16x8 ap = *(const bf16x8*)(&pl[lr][lk]);
#pragma unroll
    for (int dt = 0; dt < 4; ++dt) {
      bf16x8 bv = *(const bf16x8*)(Vb + (size_t)(dt * 16 + lr) * NT + kb + lk);
      yacc[dt] = __builtin_amdgcn_mfma_f32_16x16x32_bf16(ap, bv, yacc[dt], 0, 0, 0);
    }
    asm volatile("s_waitcnt lgkmcnt(0)" ::: "memory");
  }
#pragma unroll
  for (int dt = 0; dt < 4; ++dt)
#pragma unroll
    for (int r = 0; r < 4; ++r) {
      int qrow = q0 + lg * 4 + r;
      int d = dt * 16 + lr;
      float val = yacc[dt][r] / lrun[r];
      Y[(size_t)(b * NT + qrow) * NC + h * HD + d] = f2bf(val);
    }
}

// ---------------- workspace layout ----------------
static constexpr size_t OFF_XB = 0;                        // 4096*768*2
static constexpr size_t OFF_WT = OFF_XB + 6291456;         // 2304*768*2
static constexpr size_t OFF_WTP = OFF_WT + 3538944;        // 768*768*2
static constexpr size_t OFF_QKV = OFF_WTP + 1179648;       // 4096*2304*2
static constexpr size_t OFF_Q = OFF_QKV + 18874368;        // 48*1024*64*2
static constexpr size_t OFF_K = OFF_Q + 6291456;
static constexpr size_t OFF_VT = OFF_K + 6291456;
static constexpr size_t OFF_BIAS = OFF_VT + 6291456;       // 12*1024*257*4
static constexpr size_t OFF_Y = OFF_BIAS + 12632064;       // 4096*768*2

extern "C" void kernel_launch(void* const* d_in, const int* in_sizes, int n_in,
                              void* d_out, int out_size, void* d_ws, size_t ws_size,
                              hipStream_t stream) {
  const float* x = (const float*)d_in[0];
  const float* Wq = (const float*)d_in[1];
  const float* Wk = (const float*)d_in[2];
  const float* Wv = (const float*)d_in[3];
  const float* Wp = (const float*)d_in[4];
  const float* fw1 = (const float*)d_in[5];
  const float* fb1 = (const float*)d_in[6];
  const float* fw2 = (const float*)d_in[7];
  const float* fb2 = (const float*)d_in[8];
  const float* fc = (const float*)d_in[9];
  const float* fLm = (const float*)d_in[10];

  char* ws = (char*)d_ws;
  u16* xb = (u16*)(ws + OFF_XB);
  u16* Wt = (u16*)(ws + OFF_WT);
  u16* Wtp = (u16*)(ws + OFF_WTP);
  u16* qkv = (u16*)(ws + OFF_QKV);
  u16* Qb = (u16*)(ws + OFF_Q);
  u16* Kb = (u16*)(ws + OFF_K);
  u16* Vtb = (u16*)(ws + OFF_VT);
  float* biasb = (float*)(ws + OFF_BIAS);
  u16* Yb = (u16*)(ws + OFF_Y);

  conv_x_k<<<12288, 256, 0, stream>>>(x, xb, NB * NT * NC);
  conv_w_k<<<2304, 256, 0, stream>>>(Wq, Wk, Wv, Wp, Wt, Wtp);
  fire_bias_k<<<1024, 256, 0, stream>>>(fw1, fb1, fw2, fb2, fc, fLm, biasb);
  gemm_bt<false><<<dim3(32, 18), 256, 0, stream>>>(xb, Wt, qkv, 4096, 2304, 768);
  rope_split_k<<<12288, 256, 0, stream>>>(qkv, Qb, Kb, Vtb);
  attn_k<<<dim3(48, 16), 256, 0, stream>>>(Qb, Kb, Vtb, biasb, Yb);
  gemm_bt<true><<<dim3(32, 6), 256, 0, stream>>>(Yb, Wtp, d_out, 4096, 768, 768);
}

// Round 2
// 139.915 us; speedup vs baseline: 1.5374x; 1.5374x over previous
//
#include <hip/hip_runtime.h>

typedef unsigned short u16;
typedef __attribute__((ext_vector_type(8))) short bf16x8;
typedef __attribute__((ext_vector_type(4))) float f32x4;

#define NB 4
#define NT 1024
#define NC 768
#define NH 12
#define HD 64

__device__ __forceinline__ u16 f2bf(float f) {
  union { float f; unsigned u; } v; v.f = f;
  unsigned r = v.u + 0x7FFFu + ((v.u >> 16) & 1u);
  return (u16)(r >> 16);
}
__device__ __forceinline__ float bf2f(u16 h) {
  union { unsigned u; float f; } v; v.u = ((unsigned)h) << 16;
  return v.f;
}

__device__ __forceinline__ void gld16(const u16* g, u16* l) {
  __builtin_amdgcn_global_load_lds((const __attribute__((address_space(1))) void*)g,
                                   (__attribute__((address_space(3))) void*)l, 16, 0, 0);
}

// ---------------- conversion kernels ----------------
__global__ __launch_bounds__(256) void conv_x_k(const float* __restrict__ x,
                                                u16* __restrict__ xb, int n) {
  int i = blockIdx.x * 256 + threadIdx.x;
  if (i < n) xb[i] = f2bf(x[i]);
}

// W[k][n] fp32 -> Wt[n][k] bf16, via LDS tile transpose (coalesced both sides)
// grid (12,12,4): z selects {Wq,Wk,Wv,Wproj}
__global__ __launch_bounds__(256) void conv_w_k(const float* __restrict__ Wq,
                                                const float* __restrict__ Wk,
                                                const float* __restrict__ Wv,
                                                const float* __restrict__ Wp,
                                                u16* __restrict__ Wt,
                                                u16* __restrict__ Wtp) {
  __shared__ u16 tile[64][65];
  const float* src = (blockIdx.z == 0) ? Wq : (blockIdx.z == 1) ? Wk
                   : (blockIdx.z == 2) ? Wv : Wp;
  const int k0 = blockIdx.x * 64, n0 = blockIdx.y * 64;
  const int tid = threadIdx.x;
  const int c = tid & 63, r4 = tid >> 6;
#pragma unroll
  for (int p = 0; p < 16; ++p) {
    int kk = p * 4 + r4;
    tile[kk][c] = f2bf(src[(size_t)(k0 + kk) * NC + n0 + c]);
  }
  __syncthreads();
  u16* dst = (blockIdx.z < 3) ? (Wt + (size_t)blockIdx.z * NC * NC) : Wtp;
#pragma unroll
  for (int p = 0; p < 16; ++p) {
    int nn = p * 4 + r4;
    dst[(size_t)(n0 + nn) * NC + k0 + c] = tile[c][nn];
  }
}

// ---------------- FIRE bias table: bias[h][q][rel], rel in [0,256] ----------------
__global__ __launch_bounds__(256) void fire_bias_k(const float* __restrict__ w1,
                                                   const float* __restrict__ b1,
                                                   const float* __restrict__ w2,
                                                   const float* __restrict__ b2,
                                                   const float* __restrict__ cP,
                                                   const float* __restrict__ LmP,
                                                   float* __restrict__ bias) {
  int q = blockIdx.x;
  float c = cP[0], Lm = LmP[0];
  float thresh = fabsf(Lm * 512.0f);
  float pn = fmaxf((float)q, thresh);
  float inv_nl = 1.0f / (logf(fabsf(c * pn) + 1.0f) + 1e-6f);
  for (int rel = threadIdx.x; rel < 257; rel += 256) {
    float z = logf(fabsf(c * (float)rel) + 1.0f) * inv_nl;
    float acc[NH];
#pragma unroll
    for (int hh = 0; hh < NH; ++hh) acc[hh] = b2[hh];
#pragma unroll
    for (int j = 0; j < 32; ++j) {
      float hj = fmaxf(z * w1[j] + b1[j], 0.0f);
#pragma unroll
      for (int hh = 0; hh < NH; ++hh) acc[hh] += hj * w2[j * NH + hh];
    }
#pragma unroll
    for (int hh = 0; hh < NH; ++hh)
      bias[((size_t)hh * NT + q) * 257 + rel] = acc[hh];
  }
}

// ---------------- GEMM (m97 structure): A[M][K] bf16, Bt[N][K] bf16 ----------------
// 256 threads = 4 waves arranged WR x WC; wave tile (AI*16) x (BJ*16).
// LDS staging via global_load_lds width 16, linear [BM][32] / [BN][32] layout.
template <bool F32OUT, int WR, int WC, int AI, int BJ>
__global__ __launch_bounds__(256, 2) void gemm_lds(const u16* __restrict__ A,
                                                   const u16* __restrict__ Bt,
                                                   void* __restrict__ Cv,
                                                   int M, int N, int K) {
  constexpr int BM = WR * AI * 16;
  constexpr int BN = WC * BJ * 16;
  __shared__ u16 As[BM * 32];
  __shared__ u16 Bs[BN * 32];
  const int tid = threadIdx.x;
  const int wid = tid >> 6, lane = tid & 63;
  const int wr = wid / WC, wc = wid % WC;
  const int m0 = blockIdx.x * BM, n0 = blockIdx.y * BN;
  const int lr = lane & 15, lk = (lane >> 4) << 3;
  // staging map: issue covers 64 rows (4 waves x 16); lane -> row wid*16+(lane>>2), col (lane&3)*8
  const int srow = wid * 16 + (lane >> 2);
  const int scol = (lane & 3) * 8;
  f32x4 acc[AI][BJ] = {};
  const u16* Ag = A + (size_t)(m0 + srow) * K + scol;
  const u16* Bg = Bt + (size_t)(n0 + srow) * K + scol;
  u16* Al = &As[(wid * 16) * 32];  // wave-uniform LDS base; HW adds lane*16B
  u16* Bl = &Bs[(wid * 16) * 32];

  for (int k0 = 0; k0 < K; k0 += 32) {
#pragma unroll
    for (int ia = 0; ia < BM / 64; ++ia)
      gld16(Ag + (size_t)(ia * 64) * K + k0, Al + ia * 64 * 32);
#pragma unroll
    for (int ib = 0; ib < BN / 64; ++ib)
      gld16(Bg + (size_t)(ib * 64) * K + k0, Bl + ib * 64 * 32);
    __syncthreads();
    bf16x8 af[AI], bfv[BJ];
#pragma unroll
    for (int i = 0; i < AI; ++i)
      af[i] = *(const bf16x8*)&As[(wr * AI * 16 + i * 16 + lr) * 32 + lk];
#pragma unroll
    for (int j = 0; j < BJ; ++j)
      bfv[j] = *(const bf16x8*)&Bs[(wc * BJ * 16 + j * 16 + lr) * 32 + lk];
#pragma unroll
    for (int i = 0; i < AI; ++i)
#pragma unroll
      for (int j = 0; j < BJ; ++j)
        acc[i][j] = __builtin_amdgcn_mfma_f32_16x16x32_bf16(af[i], bfv[j], acc[i][j], 0, 0, 0);
    __syncthreads();
  }
  const int rbase = (lane >> 4) * 4;
#pragma unroll
  for (int i = 0; i < AI; ++i)
#pragma unroll
    for (int j = 0; j < BJ; ++j)
#pragma unroll
      for (int r = 0; r < 4; ++r) {
        size_t row = m0 + wr * AI * 16 + i * 16 + rbase + r;
        size_t col = n0 + wc * BJ * 16 + j * 16 + lr;
        if (F32OUT)
          ((float*)Cv)[row * N + col] = acc[i][j][r];
        else
          ((u16*)Cv)[row * N + col] = f2bf(acc[i][j][r]);
      }
}

// ---------------- RoPE + head split with LDS transpose for V ----------------
// grid (48, 16); block handles one bh x 64 t-rows; Vt write coalesced via LDS
__global__ __launch_bounds__(256) void rope_split_k(const u16* __restrict__ qkv,
                                                    u16* __restrict__ Q,
                                                    u16* __restrict__ K,
                                                    u16* __restrict__ Vt) {
  __shared__ u16 vlds[64][65];
  const int bh = blockIdx.x;
  const int t0 = blockIdx.y * 64;
  const int b = bh / NH, h = bh - b * NH;
  const int tid = threadIdx.x;
  const int d = tid & 63;
  const int i = d & 31;
  const size_t base = ((size_t)bh << 16);
  float inv = __expf(-(float)i * (0.03125f * 9.2103403719761836f));  // 10000^(-i/32)
#pragma unroll
  for (int p = 0; p < 16; ++p) {
    int tl = p * 4 + (tid >> 6);
    int t = t0 + tl;
    size_t row = (size_t)(b * NT + t) * 2304 + h * HD;
    float ang = (float)t * inv;
    float s, c;
    sincosf(ang, &s, &c);
    float qa = bf2f(qkv[row + i]);
    float qb = bf2f(qkv[row + i + 32]);
    float ka = bf2f(qkv[row + 768 + i]);
    float kb = bf2f(qkv[row + 768 + i + 32]);
    float qv = (d < 32) ? (qa * c - qb * s) : (qa * s + qb * c);
    float kv = (d < 32) ? (ka * c - kb * s) : (ka * s + kb * c);
    Q[base + (size_t)t * HD + d] = f2bf(qv);
    K[base + (size_t)t * HD + d] = f2bf(kv);
    vlds[tl][d] = qkv[row + 1536 + d];
  }
  __syncthreads();
#pragma unroll
  for (int p = 0; p < 16; ++p) {
    int dd = p * 4 + (tid >> 6);
    int tl = tid & 63;
    Vt[base + (size_t)dd * NT + t0 + tl] = vlds[tl][dd];
  }
}

// ---------------- windowed flash attention ----------------
__global__ __launch_bounds__(256) void attn_k(const u16* __restrict__ Q,
                                              const u16* __restrict__ K,
                                              const u16* __restrict__ Vt,
                                              const float* __restrict__ bias,
                                              u16* __restrict__ Y) {
  __shared__ __align__(16) u16 plds[4][16][32];
  const int bh = blockIdx.x;
  const int b = bh / NH, h = bh - b * NH;
  const int wid = threadIdx.x >> 6, lane = threadIdx.x & 63;
  const int qt = blockIdx.y * 4 + wid;
  const int q0 = qt << 4;
  const int lr = lane & 15, lg = lane >> 4, lk = (lane >> 4) << 3;
  const u16* Qb = Q + ((size_t)bh << 16);
  const u16* Kb = K + ((size_t)bh << 16);
  const u16* Vb = Vt + ((size_t)bh << 16);
  const float* biash = bias + (size_t)h * NT * 257;

  bf16x8 aq0 = *(const bf16x8*)(Qb + (q0 + lr) * HD + lk);
  bf16x8 aq1 = *(const bf16x8*)(Qb + (q0 + lr) * HD + 32 + lk);
  f32x4 yacc[4] = {};
  float mrun[4] = {-1e30f, -1e30f, -1e30f, -1e30f};
  float lrun[4] = {0.f, 0.f, 0.f, 0.f};
  u16(*pl)[32] = plds[wid];

  int kt0 = q0 - 256;
  kt0 = (kt0 > 0 ? kt0 : 0) >> 4;
  for (int kt = kt0; kt <= qt; ++kt) {
    const int kb = kt << 4;
    bf16x8 bk0 = *(const bf16x8*)(Kb + (kb + lr) * HD + lk);
    bf16x8 bk1 = *(const bf16x8*)(Kb + (kb + lr) * HD + 32 + lk);
    f32x4 s = {};
    s = __builtin_amdgcn_mfma_f32_16x16x32_bf16(aq0, bk0, s, 0, 0, 0);
    s = __builtin_amdgcn_mfma_f32_16x16x32_bf16(aq1, bk1, s, 0, 0, 0);
    const int kcol = kb + lr;
    float sv[4];
#pragma unroll
    for (int r = 0; r < 4; ++r) {
      int qrow = q0 + lg * 4 + r;
      int rel = qrow - kcol;
      if (rel >= 0 && rel <= 256)
        sv[r] = s[r] * 0.125f + biash[(size_t)qrow * 257 + rel];
      else
        sv[r] = -1e30f;
    }
    float scale[4], pexp[4];
#pragma unroll
    for (int r = 0; r < 4; ++r) {
      float m = sv[r];
#pragma unroll
      for (int off = 1; off < 16; off <<= 1)
        m = fmaxf(m, __shfl_xor(m, off, 64));
      float mn = fmaxf(mrun[r], m);
      scale[r] = __expf(mrun[r] - mn);
      mrun[r] = mn;
      pexp[r] = __expf(sv[r] - mn);
      float ss = pexp[r];
#pragma unroll
      for (int off = 1; off < 16; off <<= 1)
        ss += __shfl_xor(ss, off, 64);
      lrun[r] = lrun[r] * scale[r] + ss;
    }
#pragma unroll
    for (int dt = 0; dt < 4; ++dt)
#pragma unroll
      for (int r = 0; r < 4; ++r) yacc[dt][r] *= scale[r];
#pragma unroll
    for (int r = 0; r < 4; ++r) {
      pl[lg * 4 + r][lr] = f2bf(pexp[r]);
      pl[lg * 4 + r][16 + lr] = 0;
    }
    asm volatile("s_waitcnt lgkmcnt(0)" ::: "memory");
    bf16x8 ap = *(const bf16x8*)(&pl[lr][lk]);
#pragma unroll
    for (int dt = 0; dt < 4; ++dt) {
      bf16x8 bv = *(const bf16x8*)(Vb + (size_t)(dt * 16 + lr) * NT + kb + lk);
      yacc[dt] = __builtin_amdgcn_mfma_f32_16x16x32_bf16(ap, bv, yacc[dt], 0, 0, 0);
    }
    asm volatile("s_waitcnt lgkmcnt(0)" ::: "memory");
  }
#pragma unroll
  for (int dt = 0; dt < 4; ++dt)
#pragma unroll
    for (int r = 0; r < 4; ++r) {
      int qrow = q0 + lg * 4 + r;
      int d = dt * 16 + lr;
      float val = yacc[dt][r] / lrun[r];
      Y[(size_t)(b * NT + qrow) * NC + h * HD + d] = f2bf(val);
    }
}

// ---------------- workspace layout ----------------
static constexpr size_t OFF_XB = 0;                        // 4096*768*2
static constexpr size_t OFF_WT = OFF_XB + 6291456;         // 2304*768*2
static constexpr size_t OFF_WTP = OFF_WT + 3538944;        // 768*768*2
static constexpr size_t OFF_QKV = OFF_WTP + 1179648;       // 4096*2304*2
static constexpr size_t OFF_Q = OFF_QKV + 18874368;        // 48*1024*64*2
static constexpr size_t OFF_K = OFF_Q + 6291456;
static constexpr size_t OFF_VT = OFF_K + 6291456;
static constexpr size_t OFF_BIAS = OFF_VT + 6291456;       // 12*1024*257*4
static constexpr size_t OFF_Y = OFF_BIAS + 12632064;       // 4096*768*2

extern "C" void kernel_launch(void* const* d_in, const int* in_sizes, int n_in,
                              void* d_out, int out_size, void* d_ws, size_t ws_size,
                              hipStream_t stream) {
  const float* x = (const float*)d_in[0];
  const float* Wq = (const float*)d_in[1];
  const float* Wk = (const float*)d_in[2];
  const float* Wv = (const float*)d_in[3];
  const float* Wp = (const float*)d_in[4];
  const float* fw1 = (const float*)d_in[5];
  const float* fb1 = (const float*)d_in[6];
  const float* fw2 = (const float*)d_in[7];
  const float* fb2 = (const float*)d_in[8];
  const float* fc = (const float*)d_in[9];
  const float* fLm = (const float*)d_in[10];

  char* ws = (char*)d_ws;
  u16* xb = (u16*)(ws + OFF_XB);
  u16* Wt = (u16*)(ws + OFF_WT);
  u16* Wtp = (u16*)(ws + OFF_WTP);
  u16* qkv = (u16*)(ws + OFF_QKV);
  u16* Qb = (u16*)(ws + OFF_Q);
  u16* Kb = (u16*)(ws + OFF_K);
  u16* Vtb = (u16*)(ws + OFF_VT);
  float* biasb = (float*)(ws + OFF_BIAS);
  u16* Yb = (u16*)(ws + OFF_Y);

  conv_x_k<<<12288, 256, 0, stream>>>(x, xb, NB * NT * NC);
  conv_w_k<<<dim3(12, 12, 4), 256, 0, stream>>>(Wq, Wk, Wv, Wp, Wt, Wtp);
  fire_bias_k<<<1024, 256, 0, stream>>>(fw1, fb1, fw2, fb2, fc, fLm, biasb);
  gemm_lds<false, 2, 2, 4, 4><<<dim3(32, 18), 256, 0, stream>>>(xb, Wt, qkv, 4096, 2304, 768);
  rope_split_k<<<dim3(48, 16), 256, 0, stream>>>(qkv, Qb, Kb, Vtb);
  attn_k<<<dim3(48, 16), 256, 0, stream>>>(Qb, Kb, Vtb, biasb, Yb);
  gemm_lds<true, 1, 4, 4, 2><<<dim3(64, 6), 256, 0, stream>>>(Yb, Wtp, d_out, 4096, 768, 768);
}

// Round 3
// 132.160 us; speedup vs baseline: 1.6276x; 1.0587x over previous
//
#include <hip/hip_runtime.h>

typedef unsigned short u16;
typedef __attribute__((ext_vector_type(8))) short bf16x8;
typedef __attribute__((ext_vector_type(4))) float f32x4;

#define NB 4
#define NT 1024
#define NC 768
#define NH 12
#define HD 64

__device__ __forceinline__ u16 f2bf(float f) {
  union { float f; unsigned u; } v; v.f = f;
  unsigned r = v.u + 0x7FFFu + ((v.u >> 16) & 1u);
  return (u16)(r >> 16);
}
__device__ __forceinline__ float bf2f(u16 h) {
  union { unsigned u; float f; } v; v.u = ((unsigned)h) << 16;
  return v.f;
}

__device__ __forceinline__ void gld16(const u16* g, u16* l) {
  __builtin_amdgcn_global_load_lds((const __attribute__((address_space(1))) void*)g,
                                   (__attribute__((address_space(3))) void*)l, 16, 0, 0);
}

// ---------------- conversion kernels ----------------
__global__ __launch_bounds__(256) void conv_x_k(const float* __restrict__ x,
                                                u16* __restrict__ xb, int n) {
  int i = blockIdx.x * 256 + threadIdx.x;
  if (i < n) xb[i] = f2bf(x[i]);
}

// W[k][n] fp32 -> Wt[n][k] bf16, via LDS tile transpose (coalesced both sides)
__global__ __launch_bounds__(256) void conv_w_k(const float* __restrict__ Wq,
                                                const float* __restrict__ Wk,
                                                const float* __restrict__ Wv,
                                                const float* __restrict__ Wp,
                                                u16* __restrict__ Wt,
                                                u16* __restrict__ Wtp) {
  __shared__ u16 tile[64][65];
  const float* src = (blockIdx.z == 0) ? Wq : (blockIdx.z == 1) ? Wk
                   : (blockIdx.z == 2) ? Wv : Wp;
  const int k0 = blockIdx.x * 64, n0 = blockIdx.y * 64;
  const int tid = threadIdx.x;
  const int c = tid & 63, r4 = tid >> 6;
#pragma unroll
  for (int p = 0; p < 16; ++p) {
    int kk = p * 4 + r4;
    tile[kk][c] = f2bf(src[(size_t)(k0 + kk) * NC + n0 + c]);
  }
  __syncthreads();
  u16* dst = (blockIdx.z < 3) ? (Wt + (size_t)blockIdx.z * NC * NC) : Wtp;
#pragma unroll
  for (int p = 0; p < 16; ++p) {
    int nn = p * 4 + r4;
    dst[(size_t)(n0 + nn) * NC + k0 + c] = tile[c][nn];
  }
}

// ---------------- FIRE bias table: bias[h][q][rel], rel in [0,256] ----------------
__global__ __launch_bounds__(256) void fire_bias_k(const float* __restrict__ w1,
                                                   const float* __restrict__ b1,
                                                   const float* __restrict__ w2,
                                                   const float* __restrict__ b2,
                                                   const float* __restrict__ cP,
                                                   const float* __restrict__ LmP,
                                                   float* __restrict__ bias) {
  int q = blockIdx.x;
  float c = cP[0], Lm = LmP[0];
  float thresh = fabsf(Lm * 512.0f);
  float pn = fmaxf((float)q, thresh);
  float inv_nl = 1.0f / (logf(fabsf(c * pn) + 1.0f) + 1e-6f);
  for (int rel = threadIdx.x; rel < 257; rel += 256) {
    float z = logf(fabsf(c * (float)rel) + 1.0f) * inv_nl;
    float acc[NH];
#pragma unroll
    for (int hh = 0; hh < NH; ++hh) acc[hh] = b2[hh];
#pragma unroll
    for (int j = 0; j < 32; ++j) {
      float hj = fmaxf(z * w1[j] + b1[j], 0.0f);
#pragma unroll
      for (int hh = 0; hh < NH; ++hh) acc[hh] += hj * w2[j * NH + hh];
    }
#pragma unroll
    for (int hh = 0; hh < NH; ++hh)
      bias[((size_t)hh * NT + q) * 257 + rel] = acc[hh];
  }
}

// ---------------- GEMM (m97 structure): A[M][K] bf16, Bt[N][K] bf16 ----------------
template <bool F32OUT, int WR, int WC, int AI, int BJ>
__global__ __launch_bounds__(256, 2) void gemm_lds(const u16* __restrict__ A,
                                                   const u16* __restrict__ Bt,
                                                   void* __restrict__ Cv,
                                                   int M, int N, int K) {
  constexpr int BM = WR * AI * 16;
  constexpr int BN = WC * BJ * 16;
  __shared__ u16 As[BM * 32];
  __shared__ u16 Bs[BN * 32];
  const int tid = threadIdx.x;
  const int wid = tid >> 6, lane = tid & 63;
  const int wr = wid / WC, wc = wid % WC;
  const int m0 = blockIdx.x * BM, n0 = blockIdx.y * BN;
  const int lr = lane & 15, lk = (lane >> 4) << 3;
  const int srow = wid * 16 + (lane >> 2);
  const int scol = (lane & 3) * 8;
  f32x4 acc[AI][BJ] = {};
  const u16* Ag = A + (size_t)(m0 + srow) * K + scol;
  const u16* Bg = Bt + (size_t)(n0 + srow) * K + scol;
  u16* Al = &As[(wid * 16) * 32];
  u16* Bl = &Bs[(wid * 16) * 32];

  for (int k0 = 0; k0 < K; k0 += 32) {
#pragma unroll
    for (int ia = 0; ia < BM / 64; ++ia)
      gld16(Ag + (size_t)(ia * 64) * K + k0, Al + ia * 64 * 32);
#pragma unroll
    for (int ib = 0; ib < BN / 64; ++ib)
      gld16(Bg + (size_t)(ib * 64) * K + k0, Bl + ib * 64 * 32);
    __syncthreads();
    bf16x8 af[AI], bfv[BJ];
#pragma unroll
    for (int i = 0; i < AI; ++i)
      af[i] = *(const bf16x8*)&As[(wr * AI * 16 + i * 16 + lr) * 32 + lk];
#pragma unroll
    for (int j = 0; j < BJ; ++j)
      bfv[j] = *(const bf16x8*)&Bs[(wc * BJ * 16 + j * 16 + lr) * 32 + lk];
#pragma unroll
    for (int i = 0; i < AI; ++i)
#pragma unroll
      for (int j = 0; j < BJ; ++j)
        acc[i][j] = __builtin_amdgcn_mfma_f32_16x16x32_bf16(af[i], bfv[j], acc[i][j], 0, 0, 0);
    __syncthreads();
  }
  const int rbase = (lane >> 4) * 4;
#pragma unroll
  for (int i = 0; i < AI; ++i)
#pragma unroll
    for (int j = 0; j < BJ; ++j)
#pragma unroll
      for (int r = 0; r < 4; ++r) {
        size_t row = m0 + wr * AI * 16 + i * 16 + rbase + r;
        size_t col = n0 + wc * BJ * 16 + j * 16 + lr;
        if (F32OUT)
          ((float*)Cv)[row * N + col] = acc[i][j][r];
        else
          ((u16*)Cv)[row * N + col] = f2bf(acc[i][j][r]);
      }
}

// ---------------- RoPE + head split with LDS transpose for V ----------------
__global__ __launch_bounds__(256) void rope_split_k(const u16* __restrict__ qkv,
                                                    u16* __restrict__ Q,
                                                    u16* __restrict__ K,
                                                    u16* __restrict__ Vt) {
  __shared__ u16 vlds[64][65];
  const int bh = blockIdx.x;
  const int t0 = blockIdx.y * 64;
  const int b = bh / NH, h = bh - b * NH;
  const int tid = threadIdx.x;
  const int d = tid & 63;
  const int i = d & 31;
  const size_t base = ((size_t)bh << 16);
  float inv = __expf(-(float)i * (0.03125f * 9.2103403719761836f));
#pragma unroll
  for (int p = 0; p < 16; ++p) {
    int tl = p * 4 + (tid >> 6);
    int t = t0 + tl;
    size_t row = (size_t)(b * NT + t) * 2304 + h * HD;
    float ang = (float)t * inv;
    float s, c;
    sincosf(ang, &s, &c);
    float qa = bf2f(qkv[row + i]);
    float qb = bf2f(qkv[row + i + 32]);
    float ka = bf2f(qkv[row + 768 + i]);
    float kb = bf2f(qkv[row + 768 + i + 32]);
    float qv = (d < 32) ? (qa * c - qb * s) : (qa * s + qb * c);
    float kv = (d < 32) ? (ka * c - kb * s) : (ka * s + kb * c);
    Q[base + (size_t)t * HD + d] = f2bf(qv);
    K[base + (size_t)t * HD + d] = f2bf(kv);
    vlds[tl][d] = qkv[row + 1536 + d];
  }
  __syncthreads();
#pragma unroll
  for (int p = 0; p < 16; ++p) {
    int dd = p * 4 + (tid >> 6);
    int tl = tid & 63;
    Vt[base + (size_t)dd * NT + t0 + tl] = vlds[tl][dd];
  }
}

// ---------------- windowed flash attention, KVBLK=64 chunks ----------------
// grid (48, 16); 4 waves/block; wave handles 16 queries of one (b,h)
__global__ __launch_bounds__(256) void attn_k(const u16* __restrict__ Q,
                                              const u16* __restrict__ K,
                                              const u16* __restrict__ Vt,
                                              const float* __restrict__ bias,
                                              u16* __restrict__ Y) {
  __shared__ __align__(16) u16 plds[4][16][72];
  const int bh = blockIdx.x;
  const int b = bh / NH, h = bh - b * NH;
  const int wid = threadIdx.x >> 6, lane = threadIdx.x & 63;
  const int qt = blockIdx.y * 4 + wid;
  const int q0 = qt << 4;
  const int lr = lane & 15, lg = lane >> 4, lk = lg << 3;
  const u16* Qb = Q + ((size_t)bh << 16);
  const u16* Kb = K + ((size_t)bh << 16);
  const u16* Vb = Vt + ((size_t)bh << 16);
  const float* biash = bias + (size_t)h * NT * 257;

  bf16x8 aq0 = *(const bf16x8*)(Qb + (q0 + lr) * HD + lk);
  bf16x8 aq1 = *(const bf16x8*)(Qb + (q0 + lr) * HD + 32 + lk);
  f32x4 yacc[4] = {};
  float mrun[4] = {-1e30f, -1e30f, -1e30f, -1e30f};
  float lrun[4] = {0.f, 0.f, 0.f, 0.f};
  u16(*pl)[72] = plds[wid];

  int cstart = q0 - 256;
  if (cstart < 0) cstart = 0;
  cstart &= ~63;
  for (int c = cstart; c <= q0 + 15; c += 64) {
    // batch-issue K and V fragments for the whole 64-key chunk
    bf16x8 bk[4][2], bv[4][2];
#pragma unroll
    for (int kk = 0; kk < 4; ++kk) {
      const u16* kp = Kb + (size_t)(c + kk * 16 + lr) * HD + lk;
      bk[kk][0] = *(const bf16x8*)kp;
      bk[kk][1] = *(const bf16x8*)(kp + 32);
    }
#pragma unroll
    for (int dt = 0; dt < 4; ++dt) {
      const u16* vp = Vb + (size_t)(dt * 16 + lr) * NT + c + lk;
      bv[dt][0] = *(const bf16x8*)vp;
      bv[dt][1] = *(const bf16x8*)(vp + 32);
    }
    // scores: 4 sub-tiles of 16 keys
    float sv[4][4];  // [kk][r]
#pragma unroll
    for (int kk = 0; kk < 4; ++kk) {
      f32x4 t = {};
      t = __builtin_amdgcn_mfma_f32_16x16x32_bf16(aq0, bk[kk][0], t, 0, 0, 0);
      t = __builtin_amdgcn_mfma_f32_16x16x32_bf16(aq1, bk[kk][1], t, 0, 0, 0);
      const int kcol = c + kk * 16 + lr;
#pragma unroll
      for (int r = 0; r < 4; ++r) {
        int qrow = q0 + lg * 4 + r;
        int rel = qrow - kcol;
        sv[kk][r] = (rel >= 0 && rel <= 256)
                        ? t[r] * 0.125f + biash[(size_t)qrow * 257 + rel]
                        : -1e30f;
      }
    }
    // one online-softmax pass per 64 keys
    float scale[4];
#pragma unroll
    for (int r = 0; r < 4; ++r) {
      float m = fmaxf(fmaxf(sv[0][r], sv[1][r]), fmaxf(sv[2][r], sv[3][r]));
#pragma unroll
      for (int off = 1; off < 16; off <<= 1)
        m = fmaxf(m, __shfl_xor(m, off, 64));
      float mn = fmaxf(mrun[r], m);
      scale[r] = __expf(mrun[r] - mn);
      mrun[r] = mn;
      float ss = 0.f;
#pragma unroll
      for (int kk = 0; kk < 4; ++kk) {
        float p = __expf(sv[kk][r] - mn);
        sv[kk][r] = p;
        ss += p;
      }
#pragma unroll
      for (int off = 1; off < 16; off <<= 1)
        ss += __shfl_xor(ss, off, 64);
      lrun[r] = lrun[r] * scale[r] + ss;
    }
#pragma unroll
    for (int dt = 0; dt < 4; ++dt)
#pragma unroll
      for (int r = 0; r < 4; ++r) yacc[dt][r] *= scale[r];
    // stage P (16 q x 64 k) for the PV A-operand
#pragma unroll
    for (int kk = 0; kk < 4; ++kk)
#pragma unroll
      for (int r = 0; r < 4; ++r)
        pl[lg * 4 + r][kk * 16 + lr] = f2bf(sv[kk][r]);
    asm volatile("s_waitcnt lgkmcnt(0)" ::: "memory");
    bf16x8 ap0 = *(const bf16x8*)&pl[lr][lk];
    bf16x8 ap1 = *(const bf16x8*)&pl[lr][32 + lk];
#pragma unroll
    for (int dt = 0; dt < 4; ++dt) {
      yacc[dt] = __builtin_amdgcn_mfma_f32_16x16x32_bf16(ap0, bv[dt][0], yacc[dt], 0, 0, 0);
      yacc[dt] = __builtin_amdgcn_mfma_f32_16x16x32_bf16(ap1, bv[dt][1], yacc[dt], 0, 0, 0);
    }
    asm volatile("s_waitcnt lgkmcnt(0)" ::: "memory");
  }
  float rinv[4];
#pragma unroll
  for (int r = 0; r < 4; ++r) rinv[r] = 1.0f / lrun[r];
#pragma unroll
  for (int dt = 0; dt < 4; ++dt)
#pragma unroll
    for (int r = 0; r < 4; ++r) {
      int qrow = q0 + lg * 4 + r;
      int d = dt * 16 + lr;
      Y[(size_t)(b * NT + qrow) * NC + h * HD + d] = f2bf(yacc[dt][r] * rinv[r]);
    }
}

// ---------------- workspace layout ----------------
static constexpr size_t OFF_XB = 0;
static constexpr size_t OFF_WT = OFF_XB + 6291456;
static constexpr size_t OFF_WTP = OFF_WT + 3538944;
static constexpr size_t OFF_QKV = OFF_WTP + 1179648;
static constexpr size_t OFF_Q = OFF_QKV + 18874368;
static constexpr size_t OFF_K = OFF_Q + 6291456;
static constexpr size_t OFF_VT = OFF_K + 6291456;
static constexpr size_t OFF_BIAS = OFF_VT + 6291456;
static constexpr size_t OFF_Y = OFF_BIAS + 12632064;

extern "C" void kernel_launch(void* const* d_in, const int* in_sizes, int n_in,
                              void* d_out, int out_size, void* d_ws, size_t ws_size,
                              hipStream_t stream) {
  const float* x = (const float*)d_in[0];
  const float* Wq = (const float*)d_in[1];
  const float* Wk = (const float*)d_in[2];
  const float* Wv = (const float*)d_in[3];
  const float* Wp = (const float*)d_in[4];
  const float* fw1 = (const float*)d_in[5];
  const float* fb1 = (const float*)d_in[6];
  const float* fw2 = (const float*)d_in[7];
  const float* fb2 = (const float*)d_in[8];
  const float* fc = (const float*)d_in[9];
  const float* fLm = (const float*)d_in[10];

  char* ws = (char*)d_ws;
  u16* xb = (u16*)(ws + OFF_XB);
  u16* Wt = (u16*)(ws + OFF_WT);
  u16* Wtp = (u16*)(ws + OFF_WTP);
  u16* qkv = (u16*)(ws + OFF_QKV);
  u16* Qb = (u16*)(ws + OFF_Q);
  u16* Kb = (u16*)(ws + OFF_K);
  u16* Vtb = (u16*)(ws + OFF_VT);
  float* biasb = (float*)(ws + OFF_BIAS);
  u16* Yb = (u16*)(ws + OFF_Y);

  conv_x_k<<<12288, 256, 0, stream>>>(x, xb, NB * NT * NC);
  conv_w_k<<<dim3(12, 12, 4), 256, 0, stream>>>(Wq, Wk, Wv, Wp, Wt, Wtp);
  fire_bias_k<<<1024, 256, 0, stream>>>(fw1, fb1, fw2, fb2, fc, fLm, biasb);
  gemm_lds<false, 2, 2, 4, 4><<<dim3(32, 18), 256, 0, stream>>>(xb, Wt, qkv, 4096, 2304, 768);
  rope_split_k<<<dim3(48, 16), 256, 0, stream>>>(qkv, Qb, Kb, Vtb);
  attn_k<<<dim3(48, 16), 256, 0, stream>>>(Qb, Kb, Vtb, biasb, Yb);
  gemm_lds<true, 1, 4, 4, 2><<<dim3(64, 6), 256, 0, stream>>>(Yb, Wtp, d_out, 4096, 768, 768);
}